// Round 6
// baseline (126.476 us; speedup 1.0000x reference)
//
#include <hip/hip_runtime.h>
#include <math.h>

#define HIDDEN 128
#define MAXBUK 512
#define E1_TPB 256
#define E1_EPT 4
#define E1_EPB (E1_TPB * E1_EPT)   // 1024 edges per block
#define E1_PPB (E1_EPB * 2)        // 2048 pairs per block

// W1P layout: [64][4][36] floats (32 used + 4 pad per chunk; 16B-aligned chunks,
// slices land on distinct banks for conflict-free 4-lane ds_read_b128)
#define W1P_K_STRIDE 144
#define W1P_S_STRIDE 36
#define W1P_FLOATS   (64 * W1P_K_STRIDE)

// 4-lane quad reduction via DPP quad_perm (VALU-only, no DS pipe).
__device__ __forceinline__ float quad_add(float x)
{
    int t = __builtin_amdgcn_update_dpp(0, __float_as_int(x),
                                        0xB1, 0xF, 0xF, true); // [1,0,3,2]
    float y = x + __int_as_float(t);
    t = __builtin_amdgcn_update_dpp(0, __float_as_int(y),
                                    0x4E, 0xF, 0xF, true);     // [2,3,0,1]
    return y + __int_as_float(t);
}

// ---------------------------------------------------------------------------
// Pack + prep fused:
//   all blocks: packed[n] = (h0,h1,<c0>,<c1>); netT[n] = (rain0,rain1)
//   blocks 0..15: build W1P (transposed+padded W1)    block 0: zero counters
// ---------------------------------------------------------------------------
__global__ __launch_bounds__(256) void pack_kernel(
    const float* __restrict__ h, const float* __restrict__ rain,
    const float* __restrict__ W1,
    float* __restrict__ packed, float* __restrict__ netT,
    float* __restrict__ W1P, unsigned* __restrict__ counters, int N)
{
    const int tid = threadIdx.x;
    const int b = blockIdx.x;
    if (b < 16) {
        for (int i = tid; i < 512; i += 256) {
            const int k = 4 * b + (i >> 7);
            const int hh = i & 127;
            const int s = hh >> 5, ii = hh & 31;
            W1P[k * W1P_K_STRIDE + s * W1P_S_STRIDE + ii] = W1[hh * 64 + k];
        }
        if (b == 0)
            for (int i = tid; i < MAXBUK; i += 256) counters[i] = 0u;
    }
    const int n = b * blockDim.x + tid;
    if (n >= N) return;
    *reinterpret_cast<float2*>(&packed[4 * n]) = make_float2(h[n], h[N + n]);
    *reinterpret_cast<float2*>(&netT[2 * n])   = make_float2(rain[n], rain[N + n]);
}

// ---------------------------------------------------------------------------
// Node kernel v6: 4 rows PER THREAD x 4 slices (4-lane quad owns 4 rows).
// Each W chunk read from LDS is reused for 4 rows (4x less LDS traffic);
// quad reductions via DPP (VALU pipe, no ds_bpermute).
//   coef  = sigmoid( gelu(z@W1+b1) @ W2 + b2 ) -> packed[n].{z|w}
//   areas = softplus( z@Wa + ba )              -> areas[r]
// ---------------------------------------------------------------------------
__global__ __launch_bounds__(256) void node_kernel(
    const float* __restrict__ z,     // [R][128]
    const float* __restrict__ W1P,   // [64][4][36]
    const float* __restrict__ b1, const float* __restrict__ W2,
    const float* __restrict__ b2, const float* __restrict__ Wa,
    const float* __restrict__ ba,
    float* __restrict__ packed, float* __restrict__ areas,
    int N, int R)
{
    __shared__ float w1s[W1P_FLOATS];   // 36864 B
    __shared__ float b1s[64], w2s[64], was[128];

    const int tid = threadIdx.x;
    for (int i = tid; i < W1P_FLOATS; i += 256) w1s[i] = W1P[i];
    if (tid < 64)       b1s[tid] = b1[tid];
    else if (tid < 128) w2s[tid - 64] = W2[tid - 64];
    else if (tid < 256) was[tid - 128] = Wa[tid - 128];
    __syncthreads();

    const int slice = tid & 3;
    const int r0 = ((blockIdx.x * 256 + tid) >> 2) * 4;  // first of 4 rows

    // 4 rows x 32-float slice -> 128 VGPRs
    float zr[4][32];
#pragma unroll
    for (int j = 0; j < 4; ++j) {
        const int r = r0 + j;
        if (r < R) {
            const float4* zp = reinterpret_cast<const float4*>(
                z + (size_t)r * HIDDEN + slice * 32);
#pragma unroll
            for (int i = 0; i < 8; ++i) {
                const float4 v = zp[i];
                zr[j][4 * i + 0] = v.x; zr[j][4 * i + 1] = v.y;
                zr[j][4 * i + 2] = v.z; zr[j][4 * i + 3] = v.w;
            }
        } else {
#pragma unroll
            for (int i = 0; i < 32; ++i) zr[j][i] = 0.f;
        }
    }

    float cf[4] = {0.f, 0.f, 0.f, 0.f};
#pragma unroll 2
    for (int k = 0; k < 64; ++k) {
        const float* __restrict__ wk =
            &w1s[k * W1P_K_STRIDE + slice * W1P_S_STRIDE];
        float a0[4] = {0.f, 0.f, 0.f, 0.f};
        float a1[4] = {0.f, 0.f, 0.f, 0.f};
#pragma unroll
        for (int i = 0; i < 8; ++i) {
            const float4 w = *reinterpret_cast<const float4*>(&wk[4 * i]);
#pragma unroll
            for (int j = 0; j < 4; ++j) {           // reuse w for 4 rows
                a0[j] = fmaf(zr[j][4 * i + 0], w.x, a0[j]);
                a1[j] = fmaf(zr[j][4 * i + 1], w.y, a1[j]);
                a0[j] = fmaf(zr[j][4 * i + 2], w.z, a0[j]);
                a1[j] = fmaf(zr[j][4 * i + 3], w.w, a1[j]);
            }
        }
#pragma unroll
        for (int j = 0; j < 4; ++j) {
            const float x = quad_add(a0[j] + a1[j]) + b1s[k];
            const float g = 0.5f * x * (1.0f + erff(x * 0.70710678118654752f));
            cf[j] = fmaf(g, w2s[k], cf[j]);   // identical across the quad
        }
    }

    float ad[4];
#pragma unroll
    for (int j = 0; j < 4; ++j) {
        float t = 0.f;
#pragma unroll
        for (int i = 0; i < 32; ++i)
            t = fmaf(zr[j][i], was[slice * 32 + i], t);
        ad[j] = quad_add(t);
    }

    if (slice == 0) {
#pragma unroll
        for (int j = 0; j < 4; ++j) {
            const int r = r0 + j;
            if (r < R) {
                const float c    = 1.0f / (1.0f + expf(-(cf[j] + b2[0])));
                const float adv  = ad[j] + ba[0];
                const float area = fmaxf(adv, 0.f) + log1pf(expf(-fabsf(adv)));
                const int bb = (r >= N) ? 1 : 0;
                const int n = r - bb * N;
                packed[4 * n + 2 + bb] = c;
                areas[r] = area;
            }
        }
    }
}

// ---------------------------------------------------------------------------
// E1: per-edge flows + in-block counting-sort of (node, +/-f0,f1) pairs into
// per-bucket global segments (bucket = node>>8). ~196 int atomics per block.
// ---------------------------------------------------------------------------
__global__ __launch_bounds__(E1_TPB) void edge_bin_kernel(
    const int* __restrict__ eidx,      // [2][E]
    const float* __restrict__ packed,  // [N][4] = h0,h1,c0,c1
    float* __restrict__ flows,         // [2][E]
    unsigned* __restrict__ keysG,      // [nbuk][cap]
    float2* __restrict__ valsG,        // [nbuk][cap]
    unsigned* __restrict__ counters,   // [nbuk]
    int E, int nbuk, int cap)
{
    __shared__ unsigned hist[MAXBUK];
    __shared__ unsigned base[MAXBUK];
    __shared__ unsigned gbase[MAXBUK];
    __shared__ unsigned scan[E1_TPB];
    __shared__ unsigned skey[E1_PPB];
    __shared__ float2   sval[E1_PPB];

    const int tid = threadIdx.x;
    const int e0  = blockIdx.x * E1_EPB;

    for (int i = tid; i < nbuk; i += E1_TPB) hist[i] = 0;
    __syncthreads();

    unsigned mykey[2 * E1_EPT];
    unsigned myoff[2 * E1_EPT];
    float2   myval[2 * E1_EPT];

#pragma unroll
    for (int j = 0; j < E1_EPT; ++j) {
        const int e = e0 + j * E1_TPB + tid;
        unsigned kd = 0xFFFFFFFFu, ks = 0xFFFFFFFFu;
        float2 vd = make_float2(0.f, 0.f), vs = vd;
        if (e < E) {
            const int s = eidx[e];
            const int d = eidx[E + e];
            const float4 ps = *reinterpret_cast<const float4*>(&packed[4 * s]);
            const float4 pd = *reinterpret_cast<const float4*>(&packed[4 * d]);

            float dh = ps.x - pd.x;
            float sg = (dh > 0.f) ? 1.f : ((dh < 0.f) ? -1.f : 0.f);
            float f0 = ps.z * sg * sqrtf(fabsf(dh) + 1e-6f);
            f0 = fminf(fmaxf(f0, -10.0f), 10.0f);

            dh = ps.y - pd.y;
            sg = (dh > 0.f) ? 1.f : ((dh < 0.f) ? -1.f : 0.f);
            float f1 = ps.w * sg * sqrtf(fabsf(dh) + 1e-6f);
            f1 = fminf(fmaxf(f1, -10.0f), 10.0f);

            flows[e] = f0;
            flows[(size_t)E + e] = f1;

            kd = (unsigned)d; vd = make_float2(f0, f1);
            ks = (unsigned)s; vs = make_float2(-f0, -f1);
        }
        mykey[2 * j]     = kd; myval[2 * j]     = vd;
        mykey[2 * j + 1] = ks; myval[2 * j + 1] = vs;
        if (kd != 0xFFFFFFFFu) {
            myoff[2 * j]     = atomicAdd(&hist[kd >> 8], 1u);
            myoff[2 * j + 1] = atomicAdd(&hist[ks >> 8], 1u);
        }
    }
    __syncthreads();

    // Hillis-Steele inclusive scan of hist (nbuk <= 256)
    const unsigned hv = (tid < nbuk) ? hist[tid] : 0u;
    scan[tid] = hv;
    __syncthreads();
    for (int off = 1; off < E1_TPB; off <<= 1) {
        unsigned t = (tid >= off) ? scan[tid - off] : 0u;
        __syncthreads();
        scan[tid] += t;
        __syncthreads();
    }
    if (tid < nbuk) {
        base[tid] = scan[tid] - hv;
        if (hv > 0) gbase[tid] = atomicAdd(&counters[tid], hv);
    }
    __syncthreads();

#pragma unroll
    for (int j = 0; j < 2 * E1_EPT; ++j) {
        const unsigned k = mykey[j];
        if (k != 0xFFFFFFFFu) {
            const unsigned idx = base[k >> 8] + myoff[j];
            skey[idx] = k;
            sval[idx] = myval[j];
        }
    }
    __syncthreads();

    const int tot = 2 * min(E1_EPB, E - e0);
    for (int i = tid; i < tot; i += E1_TPB) {
        const unsigned k = skey[i];
        const unsigned bb = k >> 8;
        const unsigned pos = gbase[bb] + ((unsigned)i - base[bb]);
        if (pos < (unsigned)cap) {
            keysG[(size_t)bb * cap + pos] = k;
            valsG[(size_t)bb * cap + pos] = sval[i];
        }
    }
}

// ---------------------------------------------------------------------------
// E2: one block (512 thr) per bucket; dual LDS accumulator copies halve
// atomic serialization. Fused h-update. No global f32 atomics.
// ---------------------------------------------------------------------------
__global__ __launch_bounds__(512) void bucket_reduce_kernel(
    const unsigned* __restrict__ keysG, const float2* __restrict__ valsG,
    const unsigned* __restrict__ counters,
    const float* __restrict__ h, const float* __restrict__ rain,
    const float* __restrict__ areas,
    float* __restrict__ hnew, int N, int cap)
{
    __shared__ float accx[2][256], accy[2][256];
    const int tid = threadIdx.x;
    const int b = blockIdx.x;
    const int half = tid >> 8;
    if (tid < 256) { accx[0][tid] = 0.f; accy[0][tid] = 0.f; }
    else           { accx[1][tid - 256] = 0.f; accy[1][tid - 256] = 0.f; }
    __syncthreads();

    const int cnt = min((int)counters[b], cap);
    const unsigned* __restrict__ sk = keysG + (size_t)b * cap;
    const float2*  __restrict__  sv = valsG + (size_t)b * cap;
    for (int i = tid; i < cnt; i += 512) {
        const unsigned k = sk[i];
        const float2 v2 = sv[i];
        const int loc = (int)(k & 255u);
        atomicAdd(&accx[half][loc], v2.x);
        atomicAdd(&accy[half][loc], v2.y);
    }
    __syncthreads();

    if (tid < 256) {
        const int n = (b << 8) + tid;
        if (n < N) {
            const float net0 = rain[n]     + accx[0][tid] + accx[1][tid];
            const float net1 = rain[N + n] + accy[0][tid] + accy[1][tid];
            float dh0 = 300.0f * net0 / (areas[n] + 1e-6f);
            dh0 = fminf(fmaxf(dh0, -1.0f), 1.0f);
            hnew[n] = h[n] + dh0;
            float dh1 = 300.0f * net1 / (areas[N + n] + 1e-6f);
            dh1 = fminf(fmaxf(dh1, -1.0f), 1.0f);
            hnew[N + n] = h[N + n] + dh1;
        }
    }
}

// ---------------------------------------------------------------------------
// Fallback path (ws too small): atomic edge + update kernels.
// ---------------------------------------------------------------------------
__global__ __launch_bounds__(256) void edge_kernel(
    const int* __restrict__ eidx, const float* __restrict__ packed,
    float* __restrict__ flows, float* __restrict__ netT, int E)
{
    const int e = blockIdx.x * blockDim.x + threadIdx.x;
    if (e >= E) return;
    const int s = eidx[e];
    const int d = eidx[E + e];
    const float4 ps = *reinterpret_cast<const float4*>(&packed[4 * s]);
    const float4 pd = *reinterpret_cast<const float4*>(&packed[4 * d]);
    {
        const float dh = ps.x - pd.x;
        const float sg = (dh > 0.f) ? 1.f : ((dh < 0.f) ? -1.f : 0.f);
        float f = ps.z * sg * sqrtf(fabsf(dh) + 1e-6f);
        f = fminf(fmaxf(f, -10.0f), 10.0f);
        flows[e] = f;
        unsafeAtomicAdd(&netT[2 * d + 0],  f);
        unsafeAtomicAdd(&netT[2 * s + 0], -f);
    }
    {
        const float dh = ps.y - pd.y;
        const float sg = (dh > 0.f) ? 1.f : ((dh < 0.f) ? -1.f : 0.f);
        float f = ps.w * sg * sqrtf(fabsf(dh) + 1e-6f);
        f = fminf(fmaxf(f, -10.0f), 10.0f);
        flows[(size_t)E + e] = f;
        unsafeAtomicAdd(&netT[2 * d + 1],  f);
        unsafeAtomicAdd(&netT[2 * s + 1], -f);
    }
}

__global__ __launch_bounds__(256) void update_kernel(
    const float* __restrict__ h, const float* __restrict__ netT,
    const float* __restrict__ areas, float* __restrict__ hnew, int N)
{
    const int n = blockIdx.x * blockDim.x + threadIdx.x;
    if (n >= N) return;
    const float2 nv = *reinterpret_cast<const float2*>(&netT[2 * n]);
    float dh0 = 300.0f * nv.x / (areas[n] + 1e-6f);
    dh0 = fminf(fmaxf(dh0, -1.0f), 1.0f);
    hnew[n] = h[n] + dh0;
    float dh1 = 300.0f * nv.y / (areas[N + n] + 1e-6f);
    dh1 = fminf(fmaxf(dh1, -1.0f), 1.0f);
    hnew[N + n] = h[N + n] + dh1;
}

extern "C" void kernel_launch(void* const* d_in, const int* in_sizes, int n_in,
                              void* d_out, int out_size, void* d_ws, size_t ws_size,
                              hipStream_t stream)
{
    const float* h    = (const float*)d_in[0];
    const float* z    = (const float*)d_in[1];
    const int*   eidx = (const int*)  d_in[2];
    const float* rain = (const float*)d_in[4];
    const float* W1   = (const float*)d_in[5];
    const float* b1   = (const float*)d_in[6];
    const float* W2   = (const float*)d_in[7];
    const float* b2   = (const float*)d_in[8];
    const float* Wa   = (const float*)d_in[9];
    const float* ba   = (const float*)d_in[10];

    const int R = in_sizes[0];      // B*N
    const int E = in_sizes[3];
    const int N = R / 2;

    float* out_h     = (float*)d_out;
    float* out_flows = out_h + R;

    char* wsB = (char*)d_ws;
    size_t off = 0;
    auto take = [&](size_t bytes) -> char* {
        char* p = wsB + off;
        off = (off + bytes + 255) & ~(size_t)255;
        return p;
    };
    float*    packed   = (float*)   take((size_t)4 * N * 4);
    float*    areas    = (float*)   take((size_t)R * 4);
    float*    netT     = (float*)   take((size_t)2 * N * 4);
    float*    W1P      = (float*)   take(W1P_FLOATS * 4);
    unsigned* counters = (unsigned*)take(MAXBUK * 4);

    const int nbuk = (N + 255) >> 8;
    int cap = (int)(((size_t)2 * E / (nbuk > 0 ? nbuk : 1)) * 5 / 4 + 512);
    cap = (cap + 255) & ~255;
    unsigned* keysG = (unsigned*)take((size_t)nbuk * cap * 4);
    float2*   valsG = (float2*)  take((size_t)nbuk * cap * 8);
    const bool binned = (off <= ws_size) && (nbuk <= 256);

    const int packBlocks = max((N + 255) / 256, 16);
    pack_kernel<<<packBlocks, 256, 0, stream>>>(h, rain, W1, packed, netT,
                                                W1P, counters, N);
    node_kernel<<<(R + 255) / 256, 256, 0, stream>>>(z, W1P, b1, W2, b2, Wa, ba,
                                                     packed, areas, N, R);
    if (binned) {
        edge_bin_kernel<<<(E + E1_EPB - 1) / E1_EPB, E1_TPB, 0, stream>>>(
            eidx, packed, out_flows, keysG, valsG, counters, E, nbuk, cap);
        bucket_reduce_kernel<<<nbuk, 512, 0, stream>>>(
            keysG, valsG, counters, h, rain, areas, out_h, N, cap);
    } else {
        edge_kernel<<<(E + 255) / 256, 256, 0, stream>>>(eidx, packed,
                                                         out_flows, netT, E);
        update_kernel<<<(N + 255) / 256, 256, 0, stream>>>(h, netT, areas,
                                                           out_h, N);
    }
}

// Round 7
// 103.997 us; speedup vs baseline: 1.2162x; 1.2162x over previous
//
#include <hip/hip_runtime.h>
#include <math.h>

#define HIDDEN 128
#define MAXBUK 512
#define E1_TPB 256
#define E1_EPT 4
#define E1_EPB (E1_TPB * E1_EPT)   // 1024 edges per block
#define E1_PPB (E1_EPB * 2)        // 2048 pairs per block

// W1P layout: [64][4][36] floats (32 used + 4 pad per slice-chunk)
#define W1P_K_STRIDE 144
#define W1P_S_STRIDE 36
#define W1P_FLOATS   (64 * W1P_K_STRIDE)

// ---- DPP helpers (VALU pipe, quad-local) ----------------------------------
__device__ __forceinline__ float dpp_xor1(float v) {
    int t = __builtin_amdgcn_update_dpp(0, __float_as_int(v),
                                        0xB1, 0xF, 0xF, true); // quad_perm [1,0,3,2]
    return __int_as_float(t);
}
__device__ __forceinline__ float dpp_xor2(float v) {
    int t = __builtin_amdgcn_update_dpp(0, __float_as_int(v),
                                        0x4E, 0xF, 0xF, true); // quad_perm [2,3,0,1]
    return __int_as_float(t);
}
// lane ^ 4 exchange+add via ds_swizzle (xor_mask=4 -> offset 0x101F)
__device__ __forceinline__ float xor4_add(float v) {
    int t = __builtin_amdgcn_ds_swizzle(__float_as_int(v), 0x101F);
    return v + __int_as_float(t);
}

// fast exact-enough gelu: 0.5x(1+erf(x/sqrt2)), A&S 7.1.26, |erf err|<=2e-7
__device__ __forceinline__ float gelu_fast(float x) {
    const float u  = x * 0.70710678118654752f;
    const float au = fabsf(u);
    const float t  = __builtin_amdgcn_rcpf(fmaf(0.3275911f, au, 1.0f));
    float poly = fmaf(1.061405429f, t, -1.453152027f);
    poly = fmaf(poly, t, 1.421413741f);
    poly = fmaf(poly, t, -0.284496736f);
    poly = fmaf(poly, t, 0.254829592f);
    poly *= t;
    const float e = __expf(-au * au);
    const float erfabs = fmaf(-poly, e, 1.0f);
    const float erfv = copysignf(erfabs, u);
    return 0.5f * x * (1.0f + erfv);
}

// ---------------------------------------------------------------------------
// Pack + prep fused:
//   all blocks: packed[n] = (h0,h1,<c0>,<c1>); netT[n] = (rain0,rain1)
//   blocks 0..15: build W1P     block 0: zero counters
// ---------------------------------------------------------------------------
__global__ __launch_bounds__(256) void pack_kernel(
    const float* __restrict__ h, const float* __restrict__ rain,
    const float* __restrict__ W1,
    float* __restrict__ packed, float* __restrict__ netT,
    float* __restrict__ W1P, unsigned* __restrict__ counters, int N)
{
    const int tid = threadIdx.x;
    const int b = blockIdx.x;
    if (b < 16) {
        for (int i = tid; i < 512; i += 256) {
            const int k = 4 * b + (i >> 7);
            const int hh = i & 127;
            const int s = hh >> 5, ii = hh & 31;
            W1P[k * W1P_K_STRIDE + s * W1P_S_STRIDE + ii] = W1[hh * 64 + k];
        }
        if (b == 0)
            for (int i = tid; i < MAXBUK; i += 256) counters[i] = 0u;
    }
    const int n = b * blockDim.x + tid;
    if (n >= N) return;
    *reinterpret_cast<float2*>(&packed[4 * n]) = make_float2(h[n], h[N + n]);
    *reinterpret_cast<float2*>(&netT[2 * n])   = make_float2(rain[n], rain[N + n]);
}

// ---------------------------------------------------------------------------
// Node kernel v7: OCTET design. 8 lanes = (khalf 2) x (slice 4) own 4 rows.
//  - khalf splits the 64 k-columns (cf = sum over k is associative)
//    -> 2R threads -> ~3 waves/SIMD (was 1.5)
//  - per k: 8 ds_read_b128 reused across 4 rows; 12-inst cndmask+DPP
//    transpose-reduce leaves lane s holding ROW s's dot -> ONE gelu/lane/k
//  - khalf cf partials combined with one ds_swizzle xor4
// ---------------------------------------------------------------------------
__global__ __launch_bounds__(256) void node_kernel(
    const float* __restrict__ z,     // [R][128]
    const float* __restrict__ W1P,   // [64][4][36]
    const float* __restrict__ b1, const float* __restrict__ W2,
    const float* __restrict__ b2, const float* __restrict__ Wa,
    const float* __restrict__ ba,
    float* __restrict__ packed, float* __restrict__ areas,
    int N, int R)
{
    __shared__ float w1s[W1P_FLOATS];   // 36864 B
    __shared__ float bw[128];           // interleaved (b1[k], W2[k])
    __shared__ float was[128];

    const int tid = threadIdx.x;
    for (int i = tid; i < W1P_FLOATS; i += 256) w1s[i] = W1P[i];
    if (tid < 64)       { bw[2 * tid] = b1[tid]; bw[2 * tid + 1] = W2[tid]; }
    else if (tid < 192) was[tid - 64] = Wa[tid - 64];
    __syncthreads();

    const int s  = tid & 3;            // h-slice (32 floats)
    const int kh = (tid >> 2) & 1;     // k-half (32 of 64 cols)
    const int r0 = ((blockIdx.x * 256 + tid) >> 3) * 4;  // octet's 4 rows
    if (r0 >= R) return;

    // 4 rows x 32-float slice -> 128 VGPRs (static indices only)
    float zr[4][32];
#pragma unroll
    for (int j = 0; j < 4; ++j) {
        const int r = r0 + j;
        if (r < R) {
            const float4* zp = reinterpret_cast<const float4*>(
                z + (size_t)r * HIDDEN + s * 32);
#pragma unroll
            for (int i = 0; i < 8; ++i) {
                const float4 v = zp[i];
                zr[j][4 * i + 0] = v.x; zr[j][4 * i + 1] = v.y;
                zr[j][4 * i + 2] = v.z; zr[j][4 * i + 3] = v.w;
            }
        } else {
#pragma unroll
            for (int i = 0; i < 32; ++i) zr[j][i] = 0.f;
        }
    }

    const bool e1 = (s & 1) == 0;
    const bool e2 = (s & 2) == 0;

    float cf = 0.f;                     // row s, this k-half
    const float* __restrict__ wbase = &w1s[(kh * 32) * W1P_K_STRIDE
                                           + s * W1P_S_STRIDE];
    const float* __restrict__ bwbase = &bw[kh * 64];

    for (int t = 0; t < 32; ++t) {
        const float* __restrict__ wk = wbase + t * W1P_K_STRIDE;
        float p0 = 0.f, p1 = 0.f, p2 = 0.f, p3 = 0.f;
#pragma unroll
        for (int i = 0; i < 8; ++i) {
            const float4 w = *reinterpret_cast<const float4*>(&wk[4 * i]);
            p0 = fmaf(zr[0][4 * i + 0], w.x, p0);
            p1 = fmaf(zr[1][4 * i + 0], w.x, p1);
            p2 = fmaf(zr[2][4 * i + 0], w.x, p2);
            p3 = fmaf(zr[3][4 * i + 0], w.x, p3);
            p0 = fmaf(zr[0][4 * i + 1], w.y, p0);
            p1 = fmaf(zr[1][4 * i + 1], w.y, p1);
            p2 = fmaf(zr[2][4 * i + 1], w.y, p2);
            p3 = fmaf(zr[3][4 * i + 1], w.y, p3);
            p0 = fmaf(zr[0][4 * i + 2], w.z, p0);
            p1 = fmaf(zr[1][4 * i + 2], w.z, p1);
            p2 = fmaf(zr[2][4 * i + 2], w.z, p2);
            p3 = fmaf(zr[3][4 * i + 2], w.z, p3);
            p0 = fmaf(zr[0][4 * i + 3], w.w, p0);
            p1 = fmaf(zr[1][4 * i + 3], w.w, p1);
            p2 = fmaf(zr[2][4 * i + 3], w.w, p2);
            p3 = fmaf(zr[3][4 * i + 3], w.w, p3);
        }
        // transpose-reduce: lane s ends with FULL (4-slice) sum of ROW s
        const float a   = e1 ? p0 : p1, b = e1 ? p1 : p0;
        const float ulo = a + dpp_xor1(b);          // row (s&1) pair-sum
        const float c   = e1 ? p2 : p3, d = e1 ? p3 : p2;
        const float uhi = c + dpp_xor1(d);          // row 2+(s&1) pair-sum
        const float a2  = e2 ? ulo : uhi, b2v = e2 ? uhi : ulo;
        const float x0  = a2 + dpp_xor2(b2v);       // row s full sum

        const float2 bwk = *reinterpret_cast<const float2*>(&bwbase[2 * t]);
        const float g = gelu_fast(x0 + bwk.x);
        cf = fmaf(g, bwk.y, cf);                    // one gelu+fma per lane
    }
    const float cf_full = xor4_add(cf);             // combine k-halves

    // areas: full 32-slice dot (both k-halves compute identically)
    float q0 = 0.f, q1 = 0.f, q2 = 0.f, q3 = 0.f;
#pragma unroll
    for (int i = 0; i < 32; ++i) {
        const float wv = was[s * 32 + i];
        q0 = fmaf(zr[0][i], wv, q0);
        q1 = fmaf(zr[1][i], wv, q1);
        q2 = fmaf(zr[2][i], wv, q2);
        q3 = fmaf(zr[3][i], wv, q3);
    }
    const float aa  = e1 ? q0 : q1, ab = e1 ? q1 : q0;
    const float alo = aa + dpp_xor1(ab);
    const float ac  = e1 ? q2 : q3, adt = e1 ? q3 : q2;
    const float ahi = ac + dpp_xor1(adt);
    const float aa2 = e2 ? alo : ahi, ab2 = e2 ? ahi : alo;
    const float ad  = aa2 + dpp_xor2(ab2);          // row s z@Wa

    const int r = r0 + s;
    if (kh == 0 && r < R) {
        const float cv   = 1.0f / (1.0f + expf(-(cf_full + b2[0])));
        const float adv  = ad + ba[0];
        const float area = fmaxf(adv, 0.f) + log1pf(expf(-fabsf(adv)));
        const int bb = (r >= N) ? 1 : 0;
        const int n = r - bb * N;
        packed[4 * n + 2 + bb] = cv;
        areas[r] = area;
    }
}

// ---------------------------------------------------------------------------
// E1: per-edge flows + in-block counting-sort of (node, +/-f0,f1) pairs into
// per-bucket global segments (bucket = node>>8). ~196 int atomics per block.
// ---------------------------------------------------------------------------
__global__ __launch_bounds__(E1_TPB) void edge_bin_kernel(
    const int* __restrict__ eidx,      // [2][E]
    const float* __restrict__ packed,  // [N][4] = h0,h1,c0,c1
    float* __restrict__ flows,         // [2][E]
    unsigned* __restrict__ keysG,      // [nbuk][cap]
    float2* __restrict__ valsG,        // [nbuk][cap]
    unsigned* __restrict__ counters,   // [nbuk]
    int E, int nbuk, int cap)
{
    __shared__ unsigned hist[MAXBUK];
    __shared__ unsigned base[MAXBUK];
    __shared__ unsigned gbase[MAXBUK];
    __shared__ unsigned scan[E1_TPB];
    __shared__ unsigned skey[E1_PPB];
    __shared__ float2   sval[E1_PPB];

    const int tid = threadIdx.x;
    const int e0  = blockIdx.x * E1_EPB;

    for (int i = tid; i < nbuk; i += E1_TPB) hist[i] = 0;
    __syncthreads();

    unsigned mykey[2 * E1_EPT];
    unsigned myoff[2 * E1_EPT];
    float2   myval[2 * E1_EPT];

#pragma unroll
    for (int j = 0; j < E1_EPT; ++j) {
        const int e = e0 + j * E1_TPB + tid;
        unsigned kd = 0xFFFFFFFFu, ks = 0xFFFFFFFFu;
        float2 vd = make_float2(0.f, 0.f), vs = vd;
        if (e < E) {
            const int s = eidx[e];
            const int d = eidx[E + e];
            const float4 ps = *reinterpret_cast<const float4*>(&packed[4 * s]);
            const float4 pd = *reinterpret_cast<const float4*>(&packed[4 * d]);

            float dh = ps.x - pd.x;
            float sg = (dh > 0.f) ? 1.f : ((dh < 0.f) ? -1.f : 0.f);
            float f0 = ps.z * sg * sqrtf(fabsf(dh) + 1e-6f);
            f0 = fminf(fmaxf(f0, -10.0f), 10.0f);

            dh = ps.y - pd.y;
            sg = (dh > 0.f) ? 1.f : ((dh < 0.f) ? -1.f : 0.f);
            float f1 = ps.w * sg * sqrtf(fabsf(dh) + 1e-6f);
            f1 = fminf(fmaxf(f1, -10.0f), 10.0f);

            flows[e] = f0;
            flows[(size_t)E + e] = f1;

            kd = (unsigned)d; vd = make_float2(f0, f1);
            ks = (unsigned)s; vs = make_float2(-f0, -f1);
        }
        mykey[2 * j]     = kd; myval[2 * j]     = vd;
        mykey[2 * j + 1] = ks; myval[2 * j + 1] = vs;
        if (kd != 0xFFFFFFFFu) {
            myoff[2 * j]     = atomicAdd(&hist[kd >> 8], 1u);
            myoff[2 * j + 1] = atomicAdd(&hist[ks >> 8], 1u);
        }
    }
    __syncthreads();

    // Hillis-Steele inclusive scan of hist (nbuk <= 256)
    const unsigned hv = (tid < nbuk) ? hist[tid] : 0u;
    scan[tid] = hv;
    __syncthreads();
    for (int off = 1; off < E1_TPB; off <<= 1) {
        unsigned t = (tid >= off) ? scan[tid - off] : 0u;
        __syncthreads();
        scan[tid] += t;
        __syncthreads();
    }
    if (tid < nbuk) {
        base[tid] = scan[tid] - hv;
        if (hv > 0) gbase[tid] = atomicAdd(&counters[tid], hv);
    }
    __syncthreads();

#pragma unroll
    for (int j = 0; j < 2 * E1_EPT; ++j) {
        const unsigned k = mykey[j];
        if (k != 0xFFFFFFFFu) {
            const unsigned idx = base[k >> 8] + myoff[j];
            skey[idx] = k;
            sval[idx] = myval[j];
        }
    }
    __syncthreads();

    const int tot = 2 * min(E1_EPB, E - e0);
    for (int i = tid; i < tot; i += E1_TPB) {
        const unsigned k = skey[i];
        const unsigned bb = k >> 8;
        const unsigned pos = gbase[bb] + ((unsigned)i - base[bb]);
        if (pos < (unsigned)cap) {
            keysG[(size_t)bb * cap + pos] = k;
            valsG[(size_t)bb * cap + pos] = sval[i];
        }
    }
}

// ---------------------------------------------------------------------------
// E2: one block (512 thr) per bucket; FOUR LDS accumulator copies cut
// same-node atomic serialization. Fused h-update. No global f32 atomics.
// ---------------------------------------------------------------------------
__global__ __launch_bounds__(512) void bucket_reduce_kernel(
    const unsigned* __restrict__ keysG, const float2* __restrict__ valsG,
    const unsigned* __restrict__ counters,
    const float* __restrict__ h, const float* __restrict__ rain,
    const float* __restrict__ areas,
    float* __restrict__ hnew, int N, int cap)
{
    __shared__ float accx[4][256], accy[4][256];   // 8 KB
    const int tid = threadIdx.x;
    const int b = blockIdx.x;
    const int q = tid >> 7;                        // 4 groups of 128
    {
        float* fx = &accx[0][0];
        float* fy = &accy[0][0];
        fx[tid] = 0.f; fx[tid + 512] = 0.f;
        fy[tid] = 0.f; fy[tid + 512] = 0.f;
    }
    __syncthreads();

    const int cnt = min((int)counters[b], cap);
    const unsigned* __restrict__ sk = keysG + (size_t)b * cap;
    const float2*  __restrict__  sv = valsG + (size_t)b * cap;
    for (int i = tid; i < cnt; i += 512) {
        const unsigned k = sk[i];
        const float2 v2 = sv[i];
        const int loc = (int)(k & 255u);
        atomicAdd(&accx[q][loc], v2.x);
        atomicAdd(&accy[q][loc], v2.y);
    }
    __syncthreads();

    if (tid < 256) {
        const int n = (b << 8) + tid;
        if (n < N) {
            const float net0 = rain[n]     + ((accx[0][tid] + accx[1][tid])
                                           + (accx[2][tid] + accx[3][tid]));
            const float net1 = rain[N + n] + ((accy[0][tid] + accy[1][tid])
                                           + (accy[2][tid] + accy[3][tid]));
            float dh0 = 300.0f * net0 / (areas[n] + 1e-6f);
            dh0 = fminf(fmaxf(dh0, -1.0f), 1.0f);
            hnew[n] = h[n] + dh0;
            float dh1 = 300.0f * net1 / (areas[N + n] + 1e-6f);
            dh1 = fminf(fmaxf(dh1, -1.0f), 1.0f);
            hnew[N + n] = h[N + n] + dh1;
        }
    }
}

// ---------------------------------------------------------------------------
// Fallback path (ws too small): atomic edge + update kernels.
// ---------------------------------------------------------------------------
__global__ __launch_bounds__(256) void edge_kernel(
    const int* __restrict__ eidx, const float* __restrict__ packed,
    float* __restrict__ flows, float* __restrict__ netT, int E)
{
    const int e = blockIdx.x * blockDim.x + threadIdx.x;
    if (e >= E) return;
    const int s = eidx[e];
    const int d = eidx[E + e];
    const float4 ps = *reinterpret_cast<const float4*>(&packed[4 * s]);
    const float4 pd = *reinterpret_cast<const float4*>(&packed[4 * d]);
    {
        const float dh = ps.x - pd.x;
        const float sg = (dh > 0.f) ? 1.f : ((dh < 0.f) ? -1.f : 0.f);
        float f = ps.z * sg * sqrtf(fabsf(dh) + 1e-6f);
        f = fminf(fmaxf(f, -10.0f), 10.0f);
        flows[e] = f;
        unsafeAtomicAdd(&netT[2 * d + 0],  f);
        unsafeAtomicAdd(&netT[2 * s + 0], -f);
    }
    {
        const float dh = ps.y - pd.y;
        const float sg = (dh > 0.f) ? 1.f : ((dh < 0.f) ? -1.f : 0.f);
        float f = ps.w * sg * sqrtf(fabsf(dh) + 1e-6f);
        f = fminf(fmaxf(f, -10.0f), 10.0f);
        flows[(size_t)E + e] = f;
        unsafeAtomicAdd(&netT[2 * d + 1],  f);
        unsafeAtomicAdd(&netT[2 * s + 1], -f);
    }
}

__global__ __launch_bounds__(256) void update_kernel(
    const float* __restrict__ h, const float* __restrict__ netT,
    const float* __restrict__ areas, float* __restrict__ hnew, int N)
{
    const int n = blockIdx.x * blockDim.x + threadIdx.x;
    if (n >= N) return;
    const float2 nv = *reinterpret_cast<const float2*>(&netT[2 * n]);
    float dh0 = 300.0f * nv.x / (areas[n] + 1e-6f);
    dh0 = fminf(fmaxf(dh0, -1.0f), 1.0f);
    hnew[n] = h[n] + dh0;
    float dh1 = 300.0f * nv.y / (areas[N + n] + 1e-6f);
    dh1 = fminf(fmaxf(dh1, -1.0f), 1.0f);
    hnew[N + n] = h[N + n] + dh1;
}

extern "C" void kernel_launch(void* const* d_in, const int* in_sizes, int n_in,
                              void* d_out, int out_size, void* d_ws, size_t ws_size,
                              hipStream_t stream)
{
    const float* h    = (const float*)d_in[0];
    const float* z    = (const float*)d_in[1];
    const int*   eidx = (const int*)  d_in[2];
    const float* rain = (const float*)d_in[4];
    const float* W1   = (const float*)d_in[5];
    const float* b1   = (const float*)d_in[6];
    const float* W2   = (const float*)d_in[7];
    const float* b2   = (const float*)d_in[8];
    const float* Wa   = (const float*)d_in[9];
    const float* ba   = (const float*)d_in[10];

    const int R = in_sizes[0];      // B*N
    const int E = in_sizes[3];
    const int N = R / 2;

    float* out_h     = (float*)d_out;
    float* out_flows = out_h + R;

    char* wsB = (char*)d_ws;
    size_t off = 0;
    auto take = [&](size_t bytes) -> char* {
        char* p = wsB + off;
        off = (off + bytes + 255) & ~(size_t)255;
        return p;
    };
    float*    packed   = (float*)   take((size_t)4 * N * 4);
    float*    areas    = (float*)   take((size_t)R * 4);
    float*    netT     = (float*)   take((size_t)2 * N * 4);
    float*    W1P      = (float*)   take(W1P_FLOATS * 4);
    unsigned* counters = (unsigned*)take(MAXBUK * 4);

    const int nbuk = (N + 255) >> 8;
    int cap = (int)(((size_t)2 * E / (nbuk > 0 ? nbuk : 1)) * 5 / 4 + 512);
    cap = (cap + 255) & ~255;
    unsigned* keysG = (unsigned*)take((size_t)nbuk * cap * 4);
    float2*   valsG = (float2*)  take((size_t)nbuk * cap * 8);
    const bool binned = (off <= ws_size) && (nbuk <= 256);

    const int packBlocks = max((N + 255) / 256, 16);
    pack_kernel<<<packBlocks, 256, 0, stream>>>(h, rain, W1, packed, netT,
                                                W1P, counters, N);
    // 2R threads: 8 lanes (2 khalf x 4 slice) per 4 rows -> ceil(R/128) blocks
    node_kernel<<<(R + 127) / 128, 256, 0, stream>>>(z, W1P, b1, W2, b2, Wa, ba,
                                                     packed, areas, N, R);
    if (binned) {
        edge_bin_kernel<<<(E + E1_EPB - 1) / E1_EPB, E1_TPB, 0, stream>>>(
            eidx, packed, out_flows, keysG, valsG, counters, E, nbuk, cap);
        bucket_reduce_kernel<<<nbuk, 512, 0, stream>>>(
            keysG, valsG, counters, h, rain, areas, out_h, N, cap);
    } else {
        edge_kernel<<<(E + 255) / 256, 256, 0, stream>>>(eidx, packed,
                                                         out_flows, netT, E);
        update_kernel<<<(N + 255) / 256, 256, 0, stream>>>(h, netT, areas,
                                                           out_h, N);
    }
}

// Round 8
// 103.473 us; speedup vs baseline: 1.2223x; 1.0051x over previous
//
#include <hip/hip_runtime.h>
#include <math.h>

#define HIDDEN 128
#define MAXBUK 512
#define E1_TPB 256
#define E1_EPT 4
#define E1_EPB (E1_TPB * E1_EPT)   // 1024 edges per block
#define E1_PPB (E1_EPB * 2)        // 2048 pairs per block

// W1P layout v8: [t 0..32)][kh 0..2)][s 0..4)][36]  (idx = t*288 + kh*144 + s*36)
//  s-stride 36 = bank +4 ; kh-stride 144 = bank +16  -> octet's 8 addrs cover
//  all 32 banks -> conflict-free wave ds_read_b128.
#define W1P_T_STRIDE  288
#define W1P_KH_STRIDE 144
#define W1P_S_STRIDE  36
#define W1P_FLOATS    (32 * W1P_T_STRIDE)   // 9216 floats = 36864 B

// ---- DPP helpers (VALU pipe, quad-local) ----------------------------------
__device__ __forceinline__ float dpp_xor1(float v) {
    int t = __builtin_amdgcn_update_dpp(0, __float_as_int(v),
                                        0xB1, 0xF, 0xF, true); // quad_perm [1,0,3,2]
    return __int_as_float(t);
}
__device__ __forceinline__ float dpp_xor2(float v) {
    int t = __builtin_amdgcn_update_dpp(0, __float_as_int(v),
                                        0x4E, 0xF, 0xF, true); // quad_perm [2,3,0,1]
    return __int_as_float(t);
}
// lane ^ 4 exchange+add via ds_swizzle (xor_mask=4 -> offset 0x101F)
__device__ __forceinline__ float xor4_add(float v) {
    int t = __builtin_amdgcn_ds_swizzle(__float_as_int(v), 0x101F);
    return v + __int_as_float(t);
}

// fast gelu: 0.5x(1+erf(x/sqrt2)), A&S 7.1.26, |erf err|<=2e-7
__device__ __forceinline__ float gelu_fast(float x) {
    const float u  = x * 0.70710678118654752f;
    const float au = fabsf(u);
    const float t  = __builtin_amdgcn_rcpf(fmaf(0.3275911f, au, 1.0f));
    float poly = fmaf(1.061405429f, t, -1.453152027f);
    poly = fmaf(poly, t, 1.421413741f);
    poly = fmaf(poly, t, -0.284496736f);
    poly = fmaf(poly, t, 0.254829592f);
    poly *= t;
    const float e = __expf(-au * au);
    const float erfabs = fmaf(-poly, e, 1.0f);
    const float erfv = copysignf(erfabs, u);
    return 0.5f * x * (1.0f + erfv);
}

// ---------------------------------------------------------------------------
// Pack + prep fused:
//   all blocks: packed[n] = (h0,h1,<c0>,<c1>); netT[n] = (rain0,rain1)
//   blocks 0..15: build W1P     block 0: zero counters
// ---------------------------------------------------------------------------
__global__ __launch_bounds__(256) void pack_kernel(
    const float* __restrict__ h, const float* __restrict__ rain,
    const float* __restrict__ W1,
    float* __restrict__ packed, float* __restrict__ netT,
    float* __restrict__ W1P, unsigned* __restrict__ counters, int N)
{
    const int tid = threadIdx.x;
    const int b = blockIdx.x;
    if (b < 16) {
        for (int i = tid; i < 512; i += 256) {
            const int k = 4 * b + (i >> 7);      // global k row 0..63
            const int hh = i & 127;
            const int s = hh >> 5, ii = hh & 31;
            const int kh = k >> 5, t = k & 31;
            W1P[t * W1P_T_STRIDE + kh * W1P_KH_STRIDE + s * W1P_S_STRIDE + ii]
                = W1[hh * 64 + k];
        }
        if (b == 0)
            for (int i = tid; i < MAXBUK; i += 256) counters[i] = 0u;
    }
    const int n = b * blockDim.x + tid;
    if (n >= N) return;
    *reinterpret_cast<float2*>(&packed[4 * n]) = make_float2(h[n], h[N + n]);
    *reinterpret_cast<float2*>(&netT[2 * n])   = make_float2(rain[n], rain[N + n]);
}

// ---------------------------------------------------------------------------
// Node kernel v8: OCTET design, VGPR-resident z.
//  8 lanes = (kh 2) x (s 4) own 4 rows; zr[4][32] pinned in VGPRs via
//  __launch_bounds__(256,3) (cap ~170). Bank-spread W1P layout. No row
//  guards (R % 4 == 0). One gelu per lane per k via cndmask+DPP transpose.
// ---------------------------------------------------------------------------
__global__ __launch_bounds__(256, 3) void node_kernel(
    const float* __restrict__ z,     // [R][128]
    const float* __restrict__ W1P,   // [32][2][4][36]
    const float* __restrict__ b1, const float* __restrict__ W2,
    const float* __restrict__ b2, const float* __restrict__ Wa,
    const float* __restrict__ ba,
    float* __restrict__ packed, float* __restrict__ areas,
    int N, int R)
{
    __shared__ float w1s[W1P_FLOATS];   // 36864 B
    __shared__ float bw[128];           // interleaved (b1[k], W2[k])
    __shared__ float was[128];

    const int tid = threadIdx.x;
    for (int i = tid; i < W1P_FLOATS; i += 256) w1s[i] = W1P[i];
    if (tid < 64)       { bw[2 * tid] = b1[tid]; bw[2 * tid + 1] = W2[tid]; }
    else if (tid < 192) was[tid - 64] = Wa[tid - 64];
    __syncthreads();

    const int s  = tid & 3;            // h-slice (32 floats)
    const int kh = (tid >> 2) & 1;     // k-half (32 of 64 cols)
    const int r0 = ((blockIdx.x * 256 + tid) >> 3) * 4;  // octet's 4 rows
    if (r0 >= R) return;               // R % 4 == 0: no per-row guards needed

    // 4 rows x 32-float slice -> 128 VGPRs (static indices only)
    float zr[4][32];
#pragma unroll
    for (int j = 0; j < 4; ++j) {
        const float4* zp = reinterpret_cast<const float4*>(
            z + (size_t)(r0 + j) * HIDDEN + s * 32);
#pragma unroll
        for (int i = 0; i < 8; ++i) {
            const float4 v = zp[i];
            zr[j][4 * i + 0] = v.x; zr[j][4 * i + 1] = v.y;
            zr[j][4 * i + 2] = v.z; zr[j][4 * i + 3] = v.w;
        }
    }

    const bool e1 = (s & 1) == 0;
    const bool e2 = (s & 2) == 0;

    float cf = 0.f;                     // row s, this k-half
    const float* __restrict__ wbase =
        &w1s[kh * W1P_KH_STRIDE + s * W1P_S_STRIDE];
    const float* __restrict__ bwbase = &bw[kh * 64];

#pragma unroll 2
    for (int t = 0; t < 32; ++t) {
        const float* __restrict__ wk = wbase + t * W1P_T_STRIDE;
        float p0 = 0.f, p1 = 0.f, p2 = 0.f, p3 = 0.f;
#pragma unroll
        for (int i = 0; i < 8; ++i) {
            const float4 w = *reinterpret_cast<const float4*>(&wk[4 * i]);
            p0 = fmaf(zr[0][4 * i + 0], w.x, p0);
            p1 = fmaf(zr[1][4 * i + 0], w.x, p1);
            p2 = fmaf(zr[2][4 * i + 0], w.x, p2);
            p3 = fmaf(zr[3][4 * i + 0], w.x, p3);
            p0 = fmaf(zr[0][4 * i + 1], w.y, p0);
            p1 = fmaf(zr[1][4 * i + 1], w.y, p1);
            p2 = fmaf(zr[2][4 * i + 1], w.y, p2);
            p3 = fmaf(zr[3][4 * i + 1], w.y, p3);
            p0 = fmaf(zr[0][4 * i + 2], w.z, p0);
            p1 = fmaf(zr[1][4 * i + 2], w.z, p1);
            p2 = fmaf(zr[2][4 * i + 2], w.z, p2);
            p3 = fmaf(zr[3][4 * i + 2], w.z, p3);
            p0 = fmaf(zr[0][4 * i + 3], w.w, p0);
            p1 = fmaf(zr[1][4 * i + 3], w.w, p1);
            p2 = fmaf(zr[2][4 * i + 3], w.w, p2);
            p3 = fmaf(zr[3][4 * i + 3], w.w, p3);
        }
        // transpose-reduce: lane s ends with FULL (4-slice) sum of ROW s
        const float a   = e1 ? p0 : p1, b = e1 ? p1 : p0;
        const float ulo = a + dpp_xor1(b);
        const float c   = e1 ? p2 : p3, d = e1 ? p3 : p2;
        const float uhi = c + dpp_xor1(d);
        const float a2  = e2 ? ulo : uhi, b2v = e2 ? uhi : ulo;
        const float x0  = a2 + dpp_xor2(b2v);       // row s full sum

        const float2 bwk = *reinterpret_cast<const float2*>(&bwbase[2 * t]);
        const float g = gelu_fast(x0 + bwk.x);
        cf = fmaf(g, bwk.y, cf);                    // one gelu+fma per lane
    }
    const float cf_full = xor4_add(cf);             // combine k-halves

    // areas: full 32-slice dot (both k-halves compute identically)
    float q0 = 0.f, q1 = 0.f, q2 = 0.f, q3 = 0.f;
#pragma unroll
    for (int i = 0; i < 32; ++i) {
        const float wv = was[s * 32 + i];
        q0 = fmaf(zr[0][i], wv, q0);
        q1 = fmaf(zr[1][i], wv, q1);
        q2 = fmaf(zr[2][i], wv, q2);
        q3 = fmaf(zr[3][i], wv, q3);
    }
    const float aa  = e1 ? q0 : q1, ab = e1 ? q1 : q0;
    const float alo = aa + dpp_xor1(ab);
    const float ac  = e1 ? q2 : q3, adt = e1 ? q3 : q2;
    const float ahi = ac + dpp_xor1(adt);
    const float aa2 = e2 ? alo : ahi, ab2 = e2 ? ahi : alo;
    const float ad  = aa2 + dpp_xor2(ab2);          // row s z@Wa

    const int r = r0 + s;
    if (kh == 0) {
        const float cv   = 1.0f / (1.0f + expf(-(cf_full + b2[0])));
        const float adv  = ad + ba[0];
        const float area = fmaxf(adv, 0.f) + log1pf(expf(-fabsf(adv)));
        const int bb = (r >= N) ? 1 : 0;
        const int n = r - bb * N;
        packed[4 * n + 2 + bb] = cv;
        areas[r] = area;
    }
}

// ---------------------------------------------------------------------------
// E1: per-edge flows + in-block counting-sort of (node, +/-f0,f1) pairs into
// per-bucket global segments (bucket = node>>8). ~196 int atomics per block.
// ---------------------------------------------------------------------------
__global__ __launch_bounds__(E1_TPB) void edge_bin_kernel(
    const int* __restrict__ eidx,      // [2][E]
    const float* __restrict__ packed,  // [N][4] = h0,h1,c0,c1
    float* __restrict__ flows,         // [2][E]
    unsigned* __restrict__ keysG,      // [nbuk][cap]
    float2* __restrict__ valsG,        // [nbuk][cap]
    unsigned* __restrict__ counters,   // [nbuk]
    int E, int nbuk, int cap)
{
    __shared__ unsigned hist[MAXBUK];
    __shared__ unsigned base[MAXBUK];
    __shared__ unsigned gbase[MAXBUK];
    __shared__ unsigned scan[E1_TPB];
    __shared__ unsigned skey[E1_PPB];
    __shared__ float2   sval[E1_PPB];

    const int tid = threadIdx.x;
    const int e0  = blockIdx.x * E1_EPB;

    for (int i = tid; i < nbuk; i += E1_TPB) hist[i] = 0;
    __syncthreads();

    unsigned mykey[2 * E1_EPT];
    unsigned myoff[2 * E1_EPT];
    float2   myval[2 * E1_EPT];

#pragma unroll
    for (int j = 0; j < E1_EPT; ++j) {
        const int e = e0 + j * E1_TPB + tid;
        unsigned kd = 0xFFFFFFFFu, ks = 0xFFFFFFFFu;
        float2 vd = make_float2(0.f, 0.f), vs = vd;
        if (e < E) {
            const int s = eidx[e];
            const int d = eidx[E + e];
            const float4 ps = *reinterpret_cast<const float4*>(&packed[4 * s]);
            const float4 pd = *reinterpret_cast<const float4*>(&packed[4 * d]);

            float dh = ps.x - pd.x;
            float sg = (dh > 0.f) ? 1.f : ((dh < 0.f) ? -1.f : 0.f);
            float f0 = ps.z * sg * sqrtf(fabsf(dh) + 1e-6f);
            f0 = fminf(fmaxf(f0, -10.0f), 10.0f);

            dh = ps.y - pd.y;
            sg = (dh > 0.f) ? 1.f : ((dh < 0.f) ? -1.f : 0.f);
            float f1 = ps.w * sg * sqrtf(fabsf(dh) + 1e-6f);
            f1 = fminf(fmaxf(f1, -10.0f), 10.0f);

            flows[e] = f0;
            flows[(size_t)E + e] = f1;

            kd = (unsigned)d; vd = make_float2(f0, f1);
            ks = (unsigned)s; vs = make_float2(-f0, -f1);
        }
        mykey[2 * j]     = kd; myval[2 * j]     = vd;
        mykey[2 * j + 1] = ks; myval[2 * j + 1] = vs;
        if (kd != 0xFFFFFFFFu) {
            myoff[2 * j]     = atomicAdd(&hist[kd >> 8], 1u);
            myoff[2 * j + 1] = atomicAdd(&hist[ks >> 8], 1u);
        }
    }
    __syncthreads();

    // Hillis-Steele inclusive scan of hist (nbuk <= 256)
    const unsigned hv = (tid < nbuk) ? hist[tid] : 0u;
    scan[tid] = hv;
    __syncthreads();
    for (int off = 1; off < E1_TPB; off <<= 1) {
        unsigned t = (tid >= off) ? scan[tid - off] : 0u;
        __syncthreads();
        scan[tid] += t;
        __syncthreads();
    }
    if (tid < nbuk) {
        base[tid] = scan[tid] - hv;
        if (hv > 0) gbase[tid] = atomicAdd(&counters[tid], hv);
    }
    __syncthreads();

#pragma unroll
    for (int j = 0; j < 2 * E1_EPT; ++j) {
        const unsigned k = mykey[j];
        if (k != 0xFFFFFFFFu) {
            const unsigned idx = base[k >> 8] + myoff[j];
            skey[idx] = k;
            sval[idx] = myval[j];
        }
    }
    __syncthreads();

    const int tot = 2 * min(E1_EPB, E - e0);
    for (int i = tid; i < tot; i += E1_TPB) {
        const unsigned k = skey[i];
        const unsigned bb = k >> 8;
        const unsigned pos = gbase[bb] + ((unsigned)i - base[bb]);
        if (pos < (unsigned)cap) {
            keysG[(size_t)bb * cap + pos] = k;
            valsG[(size_t)bb * cap + pos] = sval[i];
        }
    }
}

// ---------------------------------------------------------------------------
// E2: one block (512 thr) per bucket; FOUR LDS accumulator copies cut
// same-node atomic serialization. Fused h-update. No global f32 atomics.
// ---------------------------------------------------------------------------
__global__ __launch_bounds__(512) void bucket_reduce_kernel(
    const unsigned* __restrict__ keysG, const float2* __restrict__ valsG,
    const unsigned* __restrict__ counters,
    const float* __restrict__ h, const float* __restrict__ rain,
    const float* __restrict__ areas,
    float* __restrict__ hnew, int N, int cap)
{
    __shared__ float accx[4][256], accy[4][256];   // 8 KB
    const int tid = threadIdx.x;
    const int b = blockIdx.x;
    const int q = tid >> 7;                        // 4 groups of 128
    {
        float* fx = &accx[0][0];
        float* fy = &accy[0][0];
        fx[tid] = 0.f; fx[tid + 512] = 0.f;
        fy[tid] = 0.f; fy[tid + 512] = 0.f;
    }
    __syncthreads();

    const int cnt = min((int)counters[b], cap);
    const unsigned* __restrict__ sk = keysG + (size_t)b * cap;
    const float2*  __restrict__  sv = valsG + (size_t)b * cap;
    for (int i = tid; i < cnt; i += 512) {
        const unsigned k = sk[i];
        const float2 v2 = sv[i];
        const int loc = (int)(k & 255u);
        atomicAdd(&accx[q][loc], v2.x);
        atomicAdd(&accy[q][loc], v2.y);
    }
    __syncthreads();

    if (tid < 256) {
        const int n = (b << 8) + tid;
        if (n < N) {
            const float net0 = rain[n]     + ((accx[0][tid] + accx[1][tid])
                                           + (accx[2][tid] + accx[3][tid]));
            const float net1 = rain[N + n] + ((accy[0][tid] + accy[1][tid])
                                           + (accy[2][tid] + accy[3][tid]));
            float dh0 = 300.0f * net0 / (areas[n] + 1e-6f);
            dh0 = fminf(fmaxf(dh0, -1.0f), 1.0f);
            hnew[n] = h[n] + dh0;
            float dh1 = 300.0f * net1 / (areas[N + n] + 1e-6f);
            dh1 = fminf(fmaxf(dh1, -1.0f), 1.0f);
            hnew[N + n] = h[N + n] + dh1;
        }
    }
}

// ---------------------------------------------------------------------------
// Fallback path (ws too small): atomic edge + update kernels.
// ---------------------------------------------------------------------------
__global__ __launch_bounds__(256) void edge_kernel(
    const int* __restrict__ eidx, const float* __restrict__ packed,
    float* __restrict__ flows, float* __restrict__ netT, int E)
{
    const int e = blockIdx.x * blockDim.x + threadIdx.x;
    if (e >= E) return;
    const int s = eidx[e];
    const int d = eidx[E + e];
    const float4 ps = *reinterpret_cast<const float4*>(&packed[4 * s]);
    const float4 pd = *reinterpret_cast<const float4*>(&packed[4 * d]);
    {
        const float dh = ps.x - pd.x;
        const float sg = (dh > 0.f) ? 1.f : ((dh < 0.f) ? -1.f : 0.f);
        float f = ps.z * sg * sqrtf(fabsf(dh) + 1e-6f);
        f = fminf(fmaxf(f, -10.0f), 10.0f);
        flows[e] = f;
        unsafeAtomicAdd(&netT[2 * d + 0],  f);
        unsafeAtomicAdd(&netT[2 * s + 0], -f);
    }
    {
        const float dh = ps.y - pd.y;
        const float sg = (dh > 0.f) ? 1.f : ((dh < 0.f) ? -1.f : 0.f);
        float f = ps.w * sg * sqrtf(fabsf(dh) + 1e-6f);
        f = fminf(fmaxf(f, -10.0f), 10.0f);
        flows[(size_t)E + e] = f;
        unsafeAtomicAdd(&netT[2 * d + 1],  f);
        unsafeAtomicAdd(&netT[2 * s + 1], -f);
    }
}

__global__ __launch_bounds__(256) void update_kernel(
    const float* __restrict__ h, const float* __restrict__ netT,
    const float* __restrict__ areas, float* __restrict__ hnew, int N)
{
    const int n = blockIdx.x * blockDim.x + threadIdx.x;
    if (n >= N) return;
    const float2 nv = *reinterpret_cast<const float2*>(&netT[2 * n]);
    float dh0 = 300.0f * nv.x / (areas[n] + 1e-6f);
    dh0 = fminf(fmaxf(dh0, -1.0f), 1.0f);
    hnew[n] = h[n] + dh0;
    float dh1 = 300.0f * nv.y / (areas[N + n] + 1e-6f);
    dh1 = fminf(fmaxf(dh1, -1.0f), 1.0f);
    hnew[N + n] = h[N + n] + dh1;
}

extern "C" void kernel_launch(void* const* d_in, const int* in_sizes, int n_in,
                              void* d_out, int out_size, void* d_ws, size_t ws_size,
                              hipStream_t stream)
{
    const float* h    = (const float*)d_in[0];
    const float* z    = (const float*)d_in[1];
    const int*   eidx = (const int*)  d_in[2];
    const float* rain = (const float*)d_in[4];
    const float* W1   = (const float*)d_in[5];
    const float* b1   = (const float*)d_in[6];
    const float* W2   = (const float*)d_in[7];
    const float* b2   = (const float*)d_in[8];
    const float* Wa   = (const float*)d_in[9];
    const float* ba   = (const float*)d_in[10];

    const int R = in_sizes[0];      // B*N
    const int E = in_sizes[3];
    const int N = R / 2;

    float* out_h     = (float*)d_out;
    float* out_flows = out_h + R;

    char* wsB = (char*)d_ws;
    size_t off = 0;
    auto take = [&](size_t bytes) -> char* {
        char* p = wsB + off;
        off = (off + bytes + 255) & ~(size_t)255;
        return p;
    };
    float*    packed   = (float*)   take((size_t)4 * N * 4);
    float*    areas    = (float*)   take((size_t)R * 4);
    float*    netT     = (float*)   take((size_t)2 * N * 4);
    float*    W1P      = (float*)   take(W1P_FLOATS * 4);
    unsigned* counters = (unsigned*)take(MAXBUK * 4);

    const int nbuk = (N + 255) >> 8;
    int cap = (int)(((size_t)2 * E / (nbuk > 0 ? nbuk : 1)) * 5 / 4 + 512);
    cap = (cap + 255) & ~255;
    unsigned* keysG = (unsigned*)take((size_t)nbuk * cap * 4);
    float2*   valsG = (float2*)  take((size_t)nbuk * cap * 8);
    const bool binned = (off <= ws_size) && (nbuk <= 256);

    const int packBlocks = max((N + 255) / 256, 16);
    pack_kernel<<<packBlocks, 256, 0, stream>>>(h, rain, W1, packed, netT,
                                                W1P, counters, N);
    // 2R threads: 8 lanes (2 kh x 4 s) per 4 rows -> ceil(R/128) blocks
    node_kernel<<<(R + 127) / 128, 256, 0, stream>>>(z, W1P, b1, W2, b2, Wa, ba,
                                                     packed, areas, N, R);
    if (binned) {
        edge_bin_kernel<<<(E + E1_EPB - 1) / E1_EPB, E1_TPB, 0, stream>>>(
            eidx, packed, out_flows, keysG, valsG, counters, E, nbuk, cap);
        bucket_reduce_kernel<<<nbuk, 512, 0, stream>>>(
            keysG, valsG, counters, h, rain, areas, out_h, N, cap);
    } else {
        edge_kernel<<<(E + 255) / 256, 256, 0, stream>>>(eidx, packed,
                                                         out_flows, netT, E);
        update_kernel<<<(N + 255) / 256, 256, 0, stream>>>(h, netT, areas,
                                                           out_h, N);
    }
}